// Round 2
// baseline (393.196 us; speedup 1.0000x reference)
//
#include <hip/hip_runtime.h>
#include <hip/hip_bf16.h>

#define S_LEN 4096
#define BATCH 8
#define DMODEL 1024
#define HDIM 256
#define NTYPES 8
#define KMAX 20
#define NSLOT (BATCH*KMAX)
#define THRESH 0.4f
#define LN_EPS 1e-5f
#define RSQRT2 0.70710678118654752f

// d_out offsets (f32 elements), reference return order
#define O_SCORES 0
#define O_ENH    32768
#define O_TLOG   196608
#define O_ESC    197888
#define O_TPROB  198048
#define O_TYPE   199328
#define O_VALIDK 199488

// ws layout (4-byte units)
#define WS_SCORES   0        // 32768 f32
#define WS_SPSTART  32768    // 16384 i32
#define WS_SPLEN    49152    // 16384 i32
#define WS_SPAVG    65536    // 16384 f32
#define WS_NSP      81920    // 8 i32
#define WS_SELSTART 81936    // 160 i32
#define WS_SELLEN   82096    // 160 i32
#define WS_SELAVG   82256    // 160 f32
#define WS_SELVALID 82416    // 160 f32
#define WS_REPS     82576    // 163840 f32
#define WS_G1       246416   // 40960 f32
#define WS_ENH      287376   // 163840 f32

__device__ __forceinline__ float gelu_exact(float v) {
    return 0.5f * v * (1.0f + erff(v * RSQRT2));
}

// ---------------- K1: scorer MLP over all tokens ----------------
// tile: 64 tokens x 256 hidden, 256 threads, 8x8 micro-tile, K-chunk 32
__global__ __launch_bounds__(256) void k_score(
    const float* __restrict__ X, const float* __restrict__ W1,
    const float* __restrict__ B1, const float* __restrict__ G,
    const float* __restrict__ BE, const float* __restrict__ W2,
    const float* __restrict__ B2, const int* __restrict__ MASK,
    float* __restrict__ scf, float* __restrict__ out)
{
    __shared__ float xs[32 * 72];    // [k][token], pad 72
    __shared__ float wsh[32 * 260];  // [k][col], pad 260
    __shared__ float part[64 * 33];  // LN partials
    __shared__ float mul[64];
    __shared__ float rsl[64];

    const int tid = threadIdx.x;
    const int tok0 = blockIdx.x * 64;
    const int tr = tid & 7;        // token group (8 tokens each)
    const int tc = tid >> 3;       // col group (8 cols each)
    const int lt = tid >> 2;       // loader token 0..63
    const int lks = (tid & 3) * 8; // loader k offset
    const int wr = tid >> 3;       // weight loader row 0..31
    const int wc0 = (tid & 7) * 32;

    float acc[8][8];
#pragma unroll
    for (int i = 0; i < 8; i++)
#pragma unroll
        for (int j = 0; j < 8; j++) acc[i][j] = 0.0f;

    const float* xrow = X + (size_t)(tok0 + lt) * DMODEL + lks;

    for (int k0 = 0; k0 < DMODEL; k0 += 32) {
        float4 xa = *(const float4*)(xrow + k0);
        float4 xb = *(const float4*)(xrow + k0 + 4);
        float4 wv[8];
        const float* wp = W1 + (size_t)(k0 + wr) * HDIM + wc0;
#pragma unroll
        for (int i = 0; i < 8; i++) wv[i] = *(const float4*)(wp + 4 * i);

        __syncthreads();
        xs[(lks + 0) * 72 + lt] = xa.x;
        xs[(lks + 1) * 72 + lt] = xa.y;
        xs[(lks + 2) * 72 + lt] = xa.z;
        xs[(lks + 3) * 72 + lt] = xa.w;
        xs[(lks + 4) * 72 + lt] = xb.x;
        xs[(lks + 5) * 72 + lt] = xb.y;
        xs[(lks + 6) * 72 + lt] = xb.z;
        xs[(lks + 7) * 72 + lt] = xb.w;
#pragma unroll
        for (int i = 0; i < 8; i++)
            *(float4*)&wsh[wr * 260 + wc0 + 4 * i] = wv[i];
        __syncthreads();

#pragma unroll 4
        for (int kk = 0; kk < 32; kk++) {
            const float4 a0 = *(const float4*)&xs[kk * 72 + tr * 8];
            const float4 a1 = *(const float4*)&xs[kk * 72 + tr * 8 + 4];
            const float4 b0 = *(const float4*)&wsh[kk * 260 + tc * 8];
            const float4 b1 = *(const float4*)&wsh[kk * 260 + tc * 8 + 4];
            float av[8] = {a0.x, a0.y, a0.z, a0.w, a1.x, a1.y, a1.z, a1.w};
            float bv[8] = {b0.x, b0.y, b0.z, b0.w, b1.x, b1.y, b1.z, b1.w};
#pragma unroll
            for (int i = 0; i < 8; i++)
#pragma unroll
                for (int j = 0; j < 8; j++)
                    acc[i][j] = fmaf(av[i], bv[j], acc[i][j]);
        }
    }

    // epilogue: +bias, LayerNorm over 256 cols, GELU, dot w2, sigmoid, mask
    float bia[8];
#pragma unroll
    for (int j = 0; j < 8; j++) bia[j] = B1[tc * 8 + j];
#pragma unroll
    for (int i = 0; i < 8; i++)
#pragma unroll
        for (int j = 0; j < 8; j++) acc[i][j] += bia[j];

#pragma unroll
    for (int i = 0; i < 8; i++) {
        float s = 0.0f;
#pragma unroll
        for (int j = 0; j < 8; j++) s += acc[i][j];
        part[(tr * 8 + i) * 33 + tc] = s;
    }
    __syncthreads();
    if (tid < 64) {
        float s = 0.0f;
#pragma unroll
        for (int c = 0; c < 32; c++) s += part[tid * 33 + c];
        mul[tid] = s * (1.0f / 256.0f);
    }
    __syncthreads();
    float mu[8];
#pragma unroll
    for (int i = 0; i < 8; i++) mu[i] = mul[tr * 8 + i];
#pragma unroll
    for (int i = 0; i < 8; i++) {
        float s = 0.0f;
#pragma unroll
        for (int j = 0; j < 8; j++) {
            float d = acc[i][j] - mu[i];
            s += d * d;
        }
        part[(tr * 8 + i) * 33 + tc] = s;
    }
    __syncthreads();
    if (tid < 64) {
        float s = 0.0f;
#pragma unroll
        for (int c = 0; c < 32; c++) s += part[tid * 33 + c];
        rsl[tid] = rsqrtf(s * (1.0f / 256.0f) + LN_EPS);
    }
    __syncthreads();
    float rs[8];
#pragma unroll
    for (int i = 0; i < 8; i++) rs[i] = rsl[tr * 8 + i];
    float gg[8], bb[8], ww[8];
#pragma unroll
    for (int j = 0; j < 8; j++) {
        int c = tc * 8 + j;
        gg[j] = G[c];
        bb[j] = BE[c];
        ww[j] = W2[c];
    }
#pragma unroll
    for (int i = 0; i < 8; i++) {
        float s = 0.0f;
#pragma unroll
        for (int j = 0; j < 8; j++) {
            float v = (acc[i][j] - mu[i]) * rs[i] * gg[j] + bb[j];
            s += gelu_exact(v) * ww[j];
        }
        part[(tr * 8 + i) * 33 + tc] = s;
    }
    __syncthreads();
    if (tid < 64) {
        float s = 0.0f;
#pragma unroll
        for (int c = 0; c < 32; c++) s += part[tid * 33 + c];
        float logit = s + B2[0];
        float sc = 1.0f / (1.0f + expf(-logit));
        int t = tok0 + tid;
        sc *= (float)MASK[t];
        scf[t] = sc;
        out[O_SCORES + t] = sc;
    }
}

// ---------------- K2: span RLE + top-20 per row ----------------
__global__ __launch_bounds__(1024) void k_spans(
    const float* __restrict__ scf, int* __restrict__ spstart,
    int* __restrict__ splen, float* __restrict__ spavg, int* __restrict__ nsp,
    int* __restrict__ selstart, int* __restrict__ sellen,
    float* __restrict__ selavg, float* __restrict__ selvalid,
    float* __restrict__ out)
{
    const int r = blockIdx.x, tid = threadIdx.x;
    __shared__ float sc[S_LEN];
    __shared__ unsigned char ab[S_LEN];
    __shared__ int scn[1024];
    __shared__ float avgl[2048];
    __shared__ float rv[16];
    __shared__ int ri[16];

    float4 v = ((const float4*)(scf + (size_t)r * S_LEN))[tid];
    const int s0 = tid * 4;
    sc[s0 + 0] = v.x; sc[s0 + 1] = v.y; sc[s0 + 2] = v.z; sc[s0 + 3] = v.w;
    ab[s0 + 0] = (v.x >= THRESH);
    ab[s0 + 1] = (v.y >= THRESH);
    ab[s0 + 2] = (v.z >= THRESH);
    ab[s0 + 3] = (v.w >= THRESH);
    __syncthreads();

    bool st[4];
    int cnt = 0;
#pragma unroll
    for (int i = 0; i < 4; i++) {
        bool a = ab[s0 + i] != 0;
        bool p = (s0 + i == 0) ? false : (ab[s0 + i - 1] != 0);
        st[i] = a && !p;
        cnt += st[i] ? 1 : 0;
    }
    scn[tid] = cnt;
    __syncthreads();
    for (int off = 1; off < 1024; off <<= 1) {
        int mine = scn[tid];
        int add = (tid >= off) ? scn[tid - off] : 0;
        __syncthreads();
        scn[tid] = mine + add;
        __syncthreads();
    }
    const int total = scn[1023];
    int j = scn[tid] - cnt;  // exclusive base
    for (int i = 0; i < 4; i++) {
        if (st[i]) {
            int s = s0 + i;
            float sum = 0.0f;
            int len = 0;
            int e = s;
            while (e < S_LEN && ab[e]) { sum += sc[e]; len++; e++; }
            float avg = sum / (float)len;
            spstart[r * 2048 + j] = s;
            splen[r * 2048 + j] = len;
            spavg[r * 2048 + j] = avg;
            avgl[j] = avg;
            j++;
        }
    }
    if (tid == 0) nsp[r] = total;
    __syncthreads();

    // iterative argmax (tie -> lowest index), exactly lax.top_k order
    for (int k = 0; k < KMAX; k++) {
        float bv = -3.0e38f;
        int bi = 0x7FFFFFFF;
        for (int q = tid; q < total; q += 1024) {
            float a = avgl[q];
            if (a > bv) { bv = a; bi = q; }
        }
#pragma unroll
        for (int m = 1; m < 64; m <<= 1) {
            float ov = __shfl_xor(bv, m);
            int oi = __shfl_xor(bi, m);
            if (ov > bv || (ov == bv && oi < bi)) { bv = ov; bi = oi; }
        }
        if ((tid & 63) == 0) { rv[tid >> 6] = bv; ri[tid >> 6] = bi; }
        __syncthreads();
        if (tid < 64) {
            float v2 = (tid < 16) ? rv[tid] : -3.0e38f;
            int i2 = (tid < 16) ? ri[tid] : 0x7FFFFFFF;
#pragma unroll
            for (int m = 1; m < 16; m <<= 1) {
                float ov = __shfl_xor(v2, m);
                int oi = __shfl_xor(i2, m);
                if (ov > v2 || (ov == v2 && oi < i2)) { v2 = ov; i2 = oi; }
            }
            if (tid == 0) {
                int slot = r * KMAX + k;
                if (k < total) {
                    avgl[i2] = -3.0e38f;
                    int ln = splen[r * 2048 + i2];
                    float vd = (v2 >= THRESH && ln > 0) ? 1.0f : 0.0f;
                    selstart[slot] = spstart[r * 2048 + i2];
                    sellen[slot] = ln;
                    selavg[slot] = v2;
                    selvalid[slot] = vd;
                    out[O_ESC + slot] = v2 * vd;
                    out[O_VALIDK + slot] = vd;
                } else {
                    selstart[slot] = -1;
                    sellen[slot] = 0;
                    selavg[slot] = -1.0f;
                    selvalid[slot] = 0.0f;
                    out[O_ESC + slot] = 0.0f;
                    out[O_VALIDK + slot] = 0.0f;
                }
            }
        }
        __syncthreads();
    }
}

// ---------------- K3: mean-pool hidden states over selected spans ----------------
__global__ __launch_bounds__(256) void k_pool(
    const float* __restrict__ X, const int* __restrict__ selstart,
    const int* __restrict__ sellen, const float* __restrict__ selvalid,
    float* __restrict__ reps)
{
    const int slot = blockIdx.x, tid = threadIdx.x;
    const int r = slot / KMAX;
    const int s0 = selstart[slot], ln = sellen[slot];
    const float vd = selvalid[slot];
    float a0 = 0, a1 = 0, a2 = 0, a3 = 0;
    if (s0 >= 0) {
        const float* base = X + ((size_t)r * S_LEN + s0) * DMODEL;
        for (int t = 0; t < ln; t++) {
            const float* row = base + (size_t)t * DMODEL;
            a0 += row[tid];
            a1 += row[tid + 256];
            a2 += row[tid + 512];
            a3 += row[tid + 768];
        }
    }
    const float dn = (float)((ln > 0) ? ln : 1);
    float* rp = reps + (size_t)slot * DMODEL;
    rp[tid] = a0 / dn * vd;
    rp[tid + 256] = a1 / dn * vd;
    rp[tid + 512] = a2 / dn * vd;
    rp[tid + 768] = a3 / dn * vd;
}

// ---------------- K4/K6 stage-1: X[1024] @ W[1024x256] + b -> LN -> GELU ----------------
__global__ __launch_bounds__(256) void k_mlp_h(
    const float* __restrict__ XIN, const float* __restrict__ W1,
    const float* __restrict__ B1, const float* __restrict__ G,
    const float* __restrict__ BE, float* __restrict__ OUT)
{
    const int slot = blockIdx.x, tid = threadIdx.x;
    __shared__ float xr[DMODEL];
    __shared__ float red[8];
    ((float4*)xr)[tid] = ((const float4*)(XIN + (size_t)slot * DMODEL))[tid];
    __syncthreads();
    float acc = B1[tid];
    const float* wp = W1 + tid;
#pragma unroll 16
    for (int k = 0; k < DMODEL; k++) acc += xr[k] * wp[(size_t)k * HDIM];
    // LayerNorm over 256 threads
    float s = acc;
#pragma unroll
    for (int m = 1; m < 64; m <<= 1) s += __shfl_xor(s, m);
    if ((tid & 63) == 0) red[tid >> 6] = s;
    __syncthreads();
    float mu = (red[0] + red[1] + red[2] + red[3]) * (1.0f / 256.0f);
    float d = acc - mu;
    s = d * d;
#pragma unroll
    for (int m = 1; m < 64; m <<= 1) s += __shfl_xor(s, m);
    if ((tid & 63) == 0) red[4 + (tid >> 6)] = s;
    __syncthreads();
    float var = (red[4] + red[5] + red[6] + red[7]) * (1.0f / 256.0f);
    float v = d * rsqrtf(var + LN_EPS) * G[tid] + BE[tid];
    OUT[(size_t)slot * HDIM + tid] = gelu_exact(v);
}

// ---------------- K5: G1[256] @ W2[256x1024] + b2, *valid -> ws f32 + f32 out ----------------
__global__ __launch_bounds__(256) void k_mlp_o(
    const float* __restrict__ G1, const float* __restrict__ W2,
    const float* __restrict__ B2, const float* __restrict__ selvalid,
    float* __restrict__ ENH, float* __restrict__ out)
{
    const int slot = blockIdx.x, tid = threadIdx.x;
    __shared__ float g1s[HDIM];
    g1s[tid] = G1[(size_t)slot * HDIM + tid];
    __syncthreads();
    const float vd = selvalid[slot];
    float a0 = B2[tid], a1 = B2[tid + 256], a2 = B2[tid + 512], a3 = B2[tid + 768];
    const float* wp = W2 + tid;
#pragma unroll 8
    for (int k = 0; k < HDIM; k++) {
        float g = g1s[k];
        const float* w = wp + (size_t)k * DMODEL;
        a0 += g * w[0];
        a1 += g * w[256];
        a2 += g * w[512];
        a3 += g * w[768];
    }
    a0 *= vd; a1 *= vd; a2 *= vd; a3 *= vd;
    const size_t base = (size_t)slot * DMODEL;
    ENH[base + tid] = a0;
    ENH[base + tid + 256] = a1;
    ENH[base + tid + 512] = a2;
    ENH[base + tid + 768] = a3;
    out[O_ENH + base + tid] = a0;
    out[O_ENH + base + tid + 256] = a1;
    out[O_ENH + base + tid + 512] = a2;
    out[O_ENH + base + tid + 768] = a3;
}

// ---------------- K7: type head: logits, softmax, argmax ----------------
__global__ __launch_bounds__(64) void k_type(
    const float* __restrict__ G2, const float* __restrict__ TW2,
    const float* __restrict__ TB2, float* __restrict__ out)
{
    const int slot = blockIdx.x, tid = threadIdx.x;
    __shared__ float lg[NTYPES];
    if (tid < NTYPES) {
        float acc = TB2[tid];
        const float* g2 = G2 + (size_t)slot * HDIM;
        for (int k = 0; k < HDIM; k++) acc += g2[k] * TW2[k * NTYPES + tid];
        lg[tid] = acc;
        out[O_TLOG + slot * NTYPES + tid] = acc;
    }
    __syncthreads();
    if (tid == 0) {
        float mx = lg[0];
        int am = 0;
        for (int t = 1; t < NTYPES; t++)
            if (lg[t] > mx) { mx = lg[t]; am = t; }  // strict > keeps first max
        float ex[NTYPES], ssum = 0.0f;
        for (int t = 0; t < NTYPES; t++) { ex[t] = expf(lg[t] - mx); ssum += ex[t]; }
        for (int t = 0; t < NTYPES; t++)
            out[O_TPROB + slot * NTYPES + t] = ex[t] / ssum;
        out[O_TYPE + slot] = (float)am;
    }
}

extern "C" void kernel_launch(void* const* d_in, const int* in_sizes, int n_in,
                              void* d_out, int out_size, void* d_ws, size_t ws_size,
                              hipStream_t stream) {
    const float* X = (const float*)d_in[0];
    const int* MASK = (const int*)d_in[1];
    const float* sc_w1 = (const float*)d_in[2];
    const float* sc_b1 = (const float*)d_in[3];
    const float* sc_g  = (const float*)d_in[4];
    const float* sc_be = (const float*)d_in[5];
    const float* sc_w2 = (const float*)d_in[6];
    const float* sc_b2 = (const float*)d_in[7];
    const float* en_w1 = (const float*)d_in[8];
    const float* en_b1 = (const float*)d_in[9];
    const float* en_g  = (const float*)d_in[10];
    const float* en_be = (const float*)d_in[11];
    const float* en_w2 = (const float*)d_in[12];
    const float* en_b2 = (const float*)d_in[13];
    const float* ty_w1 = (const float*)d_in[14];
    const float* ty_b1 = (const float*)d_in[15];
    const float* ty_g  = (const float*)d_in[16];
    const float* ty_be = (const float*)d_in[17];
    const float* ty_w2 = (const float*)d_in[18];
    const float* ty_b2 = (const float*)d_in[19];

    float* out = (float*)d_out;
    float* wsf = (float*)d_ws;
    int* wsi = (int*)d_ws;

    k_score<<<(BATCH * S_LEN) / 64, 256, 0, stream>>>(
        X, sc_w1, sc_b1, sc_g, sc_be, sc_w2, sc_b2, MASK, wsf + WS_SCORES, out);
    k_spans<<<BATCH, 1024, 0, stream>>>(
        wsf + WS_SCORES, wsi + WS_SPSTART, wsi + WS_SPLEN, wsf + WS_SPAVG,
        wsi + WS_NSP, wsi + WS_SELSTART, wsi + WS_SELLEN, wsf + WS_SELAVG,
        wsf + WS_SELVALID, out);
    k_pool<<<NSLOT, 256, 0, stream>>>(
        X, wsi + WS_SELSTART, wsi + WS_SELLEN, wsf + WS_SELVALID, wsf + WS_REPS);
    k_mlp_h<<<NSLOT, 256, 0, stream>>>(
        wsf + WS_REPS, en_w1, en_b1, en_g, en_be, wsf + WS_G1);
    k_mlp_o<<<NSLOT, 256, 0, stream>>>(
        wsf + WS_G1, en_w2, en_b2, wsf + WS_SELVALID, wsf + WS_ENH, out);
    k_mlp_h<<<NSLOT, 256, 0, stream>>>(
        wsf + WS_ENH, ty_w1, ty_b1, ty_g, ty_be, wsf + WS_G1);
    k_type<<<NSLOT, 64, 0, stream>>>(wsf + WS_G1, ty_w2, ty_b2, out);
}

// Round 3
// 253.905 us; speedup vs baseline: 1.5486x; 1.5486x over previous
//
#include <hip/hip_runtime.h>
#include <hip/hip_bf16.h>

#define S_LEN 4096
#define BATCH 8
#define DMODEL 1024
#define HDIM 256
#define NTYPES 8
#define KMAX 20
#define NSLOT (BATCH*KMAX)
#define THRESH 0.4f
#define LN_EPS 1e-5f
#define RSQRT2 0.70710678118654752f

// d_out offsets (f32 elements), reference return order
#define O_SCORES 0
#define O_ENH    32768
#define O_TLOG   196608
#define O_ESC    197888
#define O_TPROB  198048
#define O_TYPE   199328
#define O_VALIDK 199488

// ws layout (4-byte units)
#define WS_SCORES   0        // 32768 f32
#define WS_SPSTART  32768    // 16384 i32
#define WS_SPLEN    49152    // 16384 i32
#define WS_SPAVG    65536    // 16384 f32
#define WS_NSP      81920    // 8 i32
#define WS_SELSTART 81936    // 160 i32
#define WS_SELLEN   82096    // 160 i32
#define WS_SELAVG   82256    // 160 f32
#define WS_SELVALID 82416    // 160 f32
#define WS_REPS     82576    // 163840 f32
#define WS_G1       246416   // 40960 f32
#define WS_ENH      287376   // 163840 f32
// W1 hi/lo f16 transposed+chunked, OVERLAID on REPS..ENH region:
// only live during k_prep/k_score; k_pool (which writes REPS) runs after.
#define WS_W1TC_HI  82576    // 131072 f32 units = 262144 f16
#define WS_W1TC_LO  213648   // 131072 f32 units

typedef _Float16 f16x8 __attribute__((ext_vector_type(8)));
typedef float f32x4 __attribute__((ext_vector_type(4)));

#define APAD 40   // f16 row stride: 80 B (16-B aligned, 2-way banks only)

__device__ __forceinline__ float gelu_exact(float v) {
    return 0.5f * v * (1.0f + erff(v * RSQRT2));
}

// ---------------- K0: transpose W1 -> chunked hi/lo f16 ----------------
// TH/TL layout: [chunk=k/32][n=0..255][k%32]
__global__ __launch_bounds__(256) void k_prep(
    const float* __restrict__ W1, _Float16* __restrict__ TH,
    _Float16* __restrict__ TL)
{
    const int c = blockIdx.x;     // k-chunk 0..31
    const int n = threadIdx.x;    // 0..255
#pragma unroll
    for (int j = 0; j < 4; j++) {
        f16x8 hv, lv;
#pragma unroll
        for (int i = 0; i < 8; i++) {
            int kk = j * 8 + i;
            float w = W1[(size_t)(c * 32 + kk) * HDIM + n];  // coalesced over n
            _Float16 h = (_Float16)w;
            hv[i] = h;
            lv[i] = (_Float16)(w - (float)h);
        }
        *(f16x8*)&TH[(size_t)c * 8192 + n * 32 + j * 8] = hv;
        *(f16x8*)&TL[(size_t)c * 8192 + n * 32 + j * 8] = lv;
    }
}

// ---------------- K1: scorer MLP via split-f16 MFMA ----------------
// 512 blocks x 256 thr; tile 64 tok x 256 col; BK=32; wave tile 32x128
__global__ __launch_bounds__(256) void k_score_mfma(
    const float* __restrict__ X, const _Float16* __restrict__ TH,
    const _Float16* __restrict__ TL, const float* __restrict__ B1,
    const float* __restrict__ G, const float* __restrict__ BE,
    const float* __restrict__ W2, const float* __restrict__ B2,
    const int* __restrict__ MASK, float* __restrict__ scf,
    float* __restrict__ out)
{
    union SM {
        struct {
            _Float16 Ah[64 * APAD], Al[64 * APAD];
            _Float16 Bh[256 * APAD], Bl[256 * APAD];
        } s;
        struct { float part[64 * 33]; float mul[64]; float rsl[64]; } e;
    };
    __shared__ SM sm;

    const int tid = threadIdx.x;
    const int l = tid & 63, wid = tid >> 6;
    const int wm = (wid & 1) * 32;        // wave token offset
    const int wn = (wid >> 1) * 128;      // wave col offset
    const int fr = l & 15;                // frag row/col
    const int fq = l >> 4;                // k-quarter
    const int tok0 = blockIdx.x * 64;

    // staging indices
    const int arow = tid >> 2, aks = (tid & 3) * 8;
    const float* xrow = X + (size_t)(tok0 + arow) * DMODEL + aks;

    f32x4 acc[2][8];
#pragma unroll
    for (int mi = 0; mi < 2; mi++)
#pragma unroll
        for (int ni = 0; ni < 8; ni++) acc[mi][ni] = (f32x4)0.0f;

    for (int c = 0; c < 32; c++) {
        // issue global loads
        float4 xa = *(const float4*)(xrow + c * 32);
        float4 xb = *(const float4*)(xrow + c * 32 + 4);
        f16x8 bhv[4], blv[4];
#pragma unroll
        for (int j = 0; j < 4; j++) {
            bhv[j] = *(const f16x8*)&TH[(size_t)c * 8192 + tid * 8 + j * 2048];
            blv[j] = *(const f16x8*)&TL[(size_t)c * 8192 + tid * 8 + j * 2048];
        }
        __syncthreads();
        // convert X to hi/lo, write LDS
        float xv[8] = {xa.x, xa.y, xa.z, xa.w, xb.x, xb.y, xb.z, xb.w};
        f16x8 ah, al;
#pragma unroll
        for (int i = 0; i < 8; i++) {
            _Float16 h = (_Float16)xv[i];
            ah[i] = h;
            al[i] = (_Float16)(xv[i] - (float)h);
        }
        *(f16x8*)&sm.s.Ah[arow * APAD + aks] = ah;
        *(f16x8*)&sm.s.Al[arow * APAD + aks] = al;
#pragma unroll
        for (int j = 0; j < 4; j++) {
            int n = (tid >> 2) + j * 64;
            *(f16x8*)&sm.s.Bh[n * APAD + aks] = bhv[j];
            *(f16x8*)&sm.s.Bl[n * APAD + aks] = blv[j];
        }
        __syncthreads();
        // fragments + MFMA (3-pass split: hh + lh + hl)
        f16x8 fah[2], fal[2];
#pragma unroll
        for (int mi = 0; mi < 2; mi++) {
            fah[mi] = *(const f16x8*)&sm.s.Ah[(wm + mi * 16 + fr) * APAD + fq * 8];
            fal[mi] = *(const f16x8*)&sm.s.Al[(wm + mi * 16 + fr) * APAD + fq * 8];
        }
#pragma unroll
        for (int ni = 0; ni < 8; ni++) {
            f16x8 fbh = *(const f16x8*)&sm.s.Bh[(wn + ni * 16 + fr) * APAD + fq * 8];
            f16x8 fbl = *(const f16x8*)&sm.s.Bl[(wn + ni * 16 + fr) * APAD + fq * 8];
#pragma unroll
            for (int mi = 0; mi < 2; mi++) {
                acc[mi][ni] = __builtin_amdgcn_mfma_f32_16x16x32_f16(fah[mi], fbh, acc[mi][ni], 0, 0, 0);
                acc[mi][ni] = __builtin_amdgcn_mfma_f32_16x16x32_f16(fal[mi], fbh, acc[mi][ni], 0, 0, 0);
                acc[mi][ni] = __builtin_amdgcn_mfma_f32_16x16x32_f16(fah[mi], fbl, acc[mi][ni], 0, 0, 0);
            }
        }
    }

    __syncthreads();  // staging LDS dead; union becomes epilogue arrays

    // + bias  (C/D layout: col = wn+ni*16+fr, row = wm+mi*16+fq*4+j)
    float bcol[8];
#pragma unroll
    for (int ni = 0; ni < 8; ni++) bcol[ni] = B1[wn + ni * 16 + fr];
#pragma unroll
    for (int mi = 0; mi < 2; mi++)
#pragma unroll
        for (int ni = 0; ni < 8; ni++)
#pragma unroll
            for (int j = 0; j < 4; j++) acc[mi][ni][j] += bcol[ni];

    const int pcol = (wn >> 7) * 16 + fr;  // 0..31
    // pass 1: mean
#pragma unroll
    for (int mi = 0; mi < 2; mi++)
#pragma unroll
        for (int j = 0; j < 4; j++) {
            float s = 0.0f;
#pragma unroll
            for (int ni = 0; ni < 8; ni++) s += acc[mi][ni][j];
            sm.e.part[(wm + mi * 16 + fq * 4 + j) * 33 + pcol] = s;
        }
    __syncthreads();
    if (tid < 64) {
        float s = 0.0f;
#pragma unroll
        for (int cc = 0; cc < 32; cc++) s += sm.e.part[tid * 33 + cc];
        sm.e.mul[tid] = s * (1.0f / 256.0f);
    }
    __syncthreads();
    float mu[2][4];
#pragma unroll
    for (int mi = 0; mi < 2; mi++)
#pragma unroll
        for (int j = 0; j < 4; j++) mu[mi][j] = sm.e.mul[wm + mi * 16 + fq * 4 + j];
    // pass 2: variance
#pragma unroll
    for (int mi = 0; mi < 2; mi++)
#pragma unroll
        for (int j = 0; j < 4; j++) {
            float s = 0.0f;
#pragma unroll
            for (int ni = 0; ni < 8; ni++) {
                float d = acc[mi][ni][j] - mu[mi][j];
                s += d * d;
            }
            sm.e.part[(wm + mi * 16 + fq * 4 + j) * 33 + pcol] = s;
        }
    __syncthreads();
    if (tid < 64) {
        float s = 0.0f;
#pragma unroll
        for (int cc = 0; cc < 32; cc++) s += sm.e.part[tid * 33 + cc];
        sm.e.rsl[tid] = rsqrtf(s * (1.0f / 256.0f) + LN_EPS);
    }
    __syncthreads();
    float rs[2][4];
#pragma unroll
    for (int mi = 0; mi < 2; mi++)
#pragma unroll
        for (int j = 0; j < 4; j++) rs[mi][j] = sm.e.rsl[wm + mi * 16 + fq * 4 + j];
    // pass 3: LN affine + GELU + dot w2
    float gcol[8], becol[8], wcol[8];
#pragma unroll
    for (int ni = 0; ni < 8; ni++) {
        int cidx = wn + ni * 16 + fr;
        gcol[ni] = G[cidx];
        becol[ni] = BE[cidx];
        wcol[ni] = W2[cidx];
    }
#pragma unroll
    for (int mi = 0; mi < 2; mi++)
#pragma unroll
        for (int j = 0; j < 4; j++) {
            float s = 0.0f;
#pragma unroll
            for (int ni = 0; ni < 8; ni++) {
                float v = (acc[mi][ni][j] - mu[mi][j]) * rs[mi][j] * gcol[ni] + becol[ni];
                s += gelu_exact(v) * wcol[ni];
            }
            sm.e.part[(wm + mi * 16 + fq * 4 + j) * 33 + pcol] = s;
        }
    __syncthreads();
    if (tid < 64) {
        float s = 0.0f;
#pragma unroll
        for (int cc = 0; cc < 32; cc++) s += sm.e.part[tid * 33 + cc];
        float logit = s + B2[0];
        float sc = 1.0f / (1.0f + expf(-logit));
        int t = tok0 + tid;
        sc *= (float)MASK[t];
        scf[t] = sc;
        out[O_SCORES + t] = sc;
    }
}

// ---------------- K2: span RLE + top-20 per row ----------------
__global__ __launch_bounds__(1024) void k_spans(
    const float* __restrict__ scf, int* __restrict__ spstart,
    int* __restrict__ splen, float* __restrict__ spavg, int* __restrict__ nsp,
    int* __restrict__ selstart, int* __restrict__ sellen,
    float* __restrict__ selavg, float* __restrict__ selvalid,
    float* __restrict__ out)
{
    const int r = blockIdx.x, tid = threadIdx.x;
    __shared__ float sc[S_LEN];
    __shared__ unsigned char ab[S_LEN];
    __shared__ int scn[1024];
    __shared__ float avgl[2048];
    __shared__ float rv[16];
    __shared__ int ri[16];

    float4 v = ((const float4*)(scf + (size_t)r * S_LEN))[tid];
    const int s0 = tid * 4;
    sc[s0 + 0] = v.x; sc[s0 + 1] = v.y; sc[s0 + 2] = v.z; sc[s0 + 3] = v.w;
    ab[s0 + 0] = (v.x >= THRESH);
    ab[s0 + 1] = (v.y >= THRESH);
    ab[s0 + 2] = (v.z >= THRESH);
    ab[s0 + 3] = (v.w >= THRESH);
    __syncthreads();

    bool st[4];
    int cnt = 0;
#pragma unroll
    for (int i = 0; i < 4; i++) {
        bool a = ab[s0 + i] != 0;
        bool p = (s0 + i == 0) ? false : (ab[s0 + i - 1] != 0);
        st[i] = a && !p;
        cnt += st[i] ? 1 : 0;
    }
    scn[tid] = cnt;
    __syncthreads();
    for (int off = 1; off < 1024; off <<= 1) {
        int mine = scn[tid];
        int add = (tid >= off) ? scn[tid - off] : 0;
        __syncthreads();
        scn[tid] = mine + add;
        __syncthreads();
    }
    const int total = scn[1023];
    int j = scn[tid] - cnt;  // exclusive base
    for (int i = 0; i < 4; i++) {
        if (st[i]) {
            int s = s0 + i;
            float sum = 0.0f;
            int len = 0;
            int e = s;
            while (e < S_LEN && ab[e]) { sum += sc[e]; len++; e++; }
            float avg = sum / (float)len;
            spstart[r * 2048 + j] = s;
            splen[r * 2048 + j] = len;
            spavg[r * 2048 + j] = avg;
            avgl[j] = avg;
            j++;
        }
    }
    if (tid == 0) nsp[r] = total;
    __syncthreads();

    // iterative argmax (tie -> lowest index), exactly lax.top_k order
    for (int k = 0; k < KMAX; k++) {
        float bv = -3.0e38f;
        int bi = 0x7FFFFFFF;
        for (int q = tid; q < total; q += 1024) {
            float a = avgl[q];
            if (a > bv) { bv = a; bi = q; }
        }
#pragma unroll
        for (int m = 1; m < 64; m <<= 1) {
            float ov = __shfl_xor(bv, m);
            int oi = __shfl_xor(bi, m);
            if (ov > bv || (ov == bv && oi < bi)) { bv = ov; bi = oi; }
        }
        if ((tid & 63) == 0) { rv[tid >> 6] = bv; ri[tid >> 6] = bi; }
        __syncthreads();
        if (tid < 64) {
            float v2 = (tid < 16) ? rv[tid] : -3.0e38f;
            int i2 = (tid < 16) ? ri[tid] : 0x7FFFFFFF;
#pragma unroll
            for (int m = 1; m < 16; m <<= 1) {
                float ov = __shfl_xor(v2, m);
                int oi = __shfl_xor(i2, m);
                if (ov > v2 || (ov == v2 && oi < i2)) { v2 = ov; i2 = oi; }
            }
            if (tid == 0) {
                int slot = r * KMAX + k;
                if (k < total) {
                    avgl[i2] = -3.0e38f;
                    int ln = splen[r * 2048 + i2];
                    float vd = (v2 >= THRESH && ln > 0) ? 1.0f : 0.0f;
                    selstart[slot] = spstart[r * 2048 + i2];
                    sellen[slot] = ln;
                    selavg[slot] = v2;
                    selvalid[slot] = vd;
                    out[O_ESC + slot] = v2 * vd;
                    out[O_VALIDK + slot] = vd;
                } else {
                    selstart[slot] = -1;
                    sellen[slot] = 0;
                    selavg[slot] = -1.0f;
                    selvalid[slot] = 0.0f;
                    out[O_ESC + slot] = 0.0f;
                    out[O_VALIDK + slot] = 0.0f;
                }
            }
        }
        __syncthreads();
    }
}

// ---------------- K3: mean-pool hidden states over selected spans ----------------
__global__ __launch_bounds__(256) void k_pool(
    const float* __restrict__ X, const int* __restrict__ selstart,
    const int* __restrict__ sellen, const float* __restrict__ selvalid,
    float* __restrict__ reps)
{
    const int slot = blockIdx.x, tid = threadIdx.x;
    const int r = slot / KMAX;
    const int s0 = selstart[slot], ln = sellen[slot];
    const float vd = selvalid[slot];
    float a0 = 0, a1 = 0, a2 = 0, a3 = 0;
    if (s0 >= 0) {
        const float* base = X + ((size_t)r * S_LEN + s0) * DMODEL;
        for (int t = 0; t < ln; t++) {
            const float* row = base + (size_t)t * DMODEL;
            a0 += row[tid];
            a1 += row[tid + 256];
            a2 += row[tid + 512];
            a3 += row[tid + 768];
        }
    }
    const float dn = (float)((ln > 0) ? ln : 1);
    float* rp = reps + (size_t)slot * DMODEL;
    rp[tid] = a0 / dn * vd;
    rp[tid + 256] = a1 / dn * vd;
    rp[tid + 512] = a2 / dn * vd;
    rp[tid + 768] = a3 / dn * vd;
}

// ---------------- K4/K6 stage-1: X[1024] @ W[1024x256] + b -> LN -> GELU ----------------
__global__ __launch_bounds__(256) void k_mlp_h(
    const float* __restrict__ XIN, const float* __restrict__ W1,
    const float* __restrict__ B1, const float* __restrict__ G,
    const float* __restrict__ BE, float* __restrict__ OUT)
{
    const int slot = blockIdx.x, tid = threadIdx.x;
    __shared__ float xr[DMODEL];
    __shared__ float red[8];
    ((float4*)xr)[tid] = ((const float4*)(XIN + (size_t)slot * DMODEL))[tid];
    __syncthreads();
    float acc = B1[tid];
    const float* wp = W1 + tid;
#pragma unroll 16
    for (int k = 0; k < DMODEL; k++) acc += xr[k] * wp[(size_t)k * HDIM];
    // LayerNorm over 256 threads
    float s = acc;
#pragma unroll
    for (int m = 1; m < 64; m <<= 1) s += __shfl_xor(s, m);
    if ((tid & 63) == 0) red[tid >> 6] = s;
    __syncthreads();
    float mu = (red[0] + red[1] + red[2] + red[3]) * (1.0f / 256.0f);
    float d = acc - mu;
    s = d * d;
#pragma unroll
    for (int m = 1; m < 64; m <<= 1) s += __shfl_xor(s, m);
    if ((tid & 63) == 0) red[4 + (tid >> 6)] = s;
    __syncthreads();
    float var = (red[4] + red[5] + red[6] + red[7]) * (1.0f / 256.0f);
    float v = d * rsqrtf(var + LN_EPS) * G[tid] + BE[tid];
    OUT[(size_t)slot * HDIM + tid] = gelu_exact(v);
}

// ---------------- K5: G1[256] @ W2[256x1024] + b2, *valid -> ws f32 + f32 out ----------------
__global__ __launch_bounds__(256) void k_mlp_o(
    const float* __restrict__ G1, const float* __restrict__ W2,
    const float* __restrict__ B2, const float* __restrict__ selvalid,
    float* __restrict__ ENH, float* __restrict__ out)
{
    const int slot = blockIdx.x, tid = threadIdx.x;
    __shared__ float g1s[HDIM];
    g1s[tid] = G1[(size_t)slot * HDIM + tid];
    __syncthreads();
    const float vd = selvalid[slot];
    float a0 = B2[tid], a1 = B2[tid + 256], a2 = B2[tid + 512], a3 = B2[tid + 768];
    const float* wp = W2 + tid;
#pragma unroll 8
    for (int k = 0; k < HDIM; k++) {
        float g = g1s[k];
        const float* w = wp + (size_t)k * DMODEL;
        a0 += g * w[0];
        a1 += g * w[256];
        a2 += g * w[512];
        a3 += g * w[768];
    }
    a0 *= vd; a1 *= vd; a2 *= vd; a3 *= vd;
    const size_t base = (size_t)slot * DMODEL;
    ENH[base + tid] = a0;
    ENH[base + tid + 256] = a1;
    ENH[base + tid + 512] = a2;
    ENH[base + tid + 768] = a3;
    out[O_ENH + base + tid] = a0;
    out[O_ENH + base + tid + 256] = a1;
    out[O_ENH + base + tid + 512] = a2;
    out[O_ENH + base + tid + 768] = a3;
}

// ---------------- K7: type head: logits, softmax, argmax ----------------
__global__ __launch_bounds__(64) void k_type(
    const float* __restrict__ G2, const float* __restrict__ TW2,
    const float* __restrict__ TB2, float* __restrict__ out)
{
    const int slot = blockIdx.x, tid = threadIdx.x;
    __shared__ float lg[NTYPES];
    if (tid < NTYPES) {
        float acc = TB2[tid];
        const float* g2 = G2 + (size_t)slot * HDIM;
        for (int k = 0; k < HDIM; k++) acc += g2[k] * TW2[k * NTYPES + tid];
        lg[tid] = acc;
        out[O_TLOG + slot * NTYPES + tid] = acc;
    }
    __syncthreads();
    if (tid == 0) {
        float mx = lg[0];
        int am = 0;
        for (int t = 1; t < NTYPES; t++)
            if (lg[t] > mx) { mx = lg[t]; am = t; }  // strict > keeps first max
        float ex[NTYPES], ssum = 0.0f;
        for (int t = 0; t < NTYPES; t++) { ex[t] = expf(lg[t] - mx); ssum += ex[t]; }
        for (int t = 0; t < NTYPES; t++)
            out[O_TPROB + slot * NTYPES + t] = ex[t] / ssum;
        out[O_TYPE + slot] = (float)am;
    }
}

extern "C" void kernel_launch(void* const* d_in, const int* in_sizes, int n_in,
                              void* d_out, int out_size, void* d_ws, size_t ws_size,
                              hipStream_t stream) {
    const float* X = (const float*)d_in[0];
    const int* MASK = (const int*)d_in[1];
    const float* sc_w1 = (const float*)d_in[2];
    const float* sc_b1 = (const float*)d_in[3];
    const float* sc_g  = (const float*)d_in[4];
    const float* sc_be = (const float*)d_in[5];
    const float* sc_w2 = (const float*)d_in[6];
    const float* sc_b2 = (const float*)d_in[7];
    const float* en_w1 = (const float*)d_in[8];
    const float* en_b1 = (const float*)d_in[9];
    const float* en_g  = (const float*)d_in[10];
    const float* en_be = (const float*)d_in[11];
    const float* en_w2 = (const float*)d_in[12];
    const float* en_b2 = (const float*)d_in[13];
    const float* ty_w1 = (const float*)d_in[14];
    const float* ty_b1 = (const float*)d_in[15];
    const float* ty_g  = (const float*)d_in[16];
    const float* ty_be = (const float*)d_in[17];
    const float* ty_w2 = (const float*)d_in[18];
    const float* ty_b2 = (const float*)d_in[19];

    float* out = (float*)d_out;
    float* wsf = (float*)d_ws;
    int* wsi = (int*)d_ws;
    _Float16* w1tc_hi = (_Float16*)(wsf + WS_W1TC_HI);
    _Float16* w1tc_lo = (_Float16*)(wsf + WS_W1TC_LO);

    k_prep<<<32, 256, 0, stream>>>(sc_w1, w1tc_hi, w1tc_lo);
    k_score_mfma<<<(BATCH * S_LEN) / 64, 256, 0, stream>>>(
        X, w1tc_hi, w1tc_lo, sc_b1, sc_g, sc_be, sc_w2, sc_b2, MASK,
        wsf + WS_SCORES, out);
    k_spans<<<BATCH, 1024, 0, stream>>>(
        wsf + WS_SCORES, wsi + WS_SPSTART, wsi + WS_SPLEN, wsf + WS_SPAVG,
        wsi + WS_NSP, wsi + WS_SELSTART, wsi + WS_SELLEN, wsf + WS_SELAVG,
        wsf + WS_SELVALID, out);
    k_pool<<<NSLOT, 256, 0, stream>>>(
        X, wsi + WS_SELSTART, wsi + WS_SELLEN, wsf + WS_SELVALID, wsf + WS_REPS);
    k_mlp_h<<<NSLOT, 256, 0, stream>>>(
        wsf + WS_REPS, en_w1, en_b1, en_g, en_be, wsf + WS_G1);
    k_mlp_o<<<NSLOT, 256, 0, stream>>>(
        wsf + WS_G1, en_w2, en_b2, wsf + WS_SELVALID, wsf + WS_ENH, out);
    k_mlp_h<<<NSLOT, 256, 0, stream>>>(
        wsf + WS_ENH, ty_w1, ty_b1, ty_g, ty_be, wsf + WS_G1);
    k_type<<<NSLOT, 64, 0, stream>>>(wsf + WS_G1, ty_w2, ty_b2, out);
}